// Round 3
// baseline (351.445 us; speedup 1.0000x reference)
//
#include <hip/hip_runtime.h>

namespace {
constexpr int B    = 32;
constexpr int CIN  = 64;
constexpr int H    = 128;
constexpr int L    = 4096;
constexpr int TL   = 96;            // output positions per tile
constexpr int NCOL = 30 + TL;       // 126 valid columns
constexpr int NTILES = (L + TL - 1) / TL;  // 43
constexpr float EPS = 1e-5f;
}

// Position-major swizzled LDS: float index of (pos j, channel c).
// XOR of channel bits [2:4] with row bits [0:2] -> 8 consecutive rows map the
// same 4-channel chunk to 8 distinct bank-quads: ds_*_b128 conflict-free.
__device__ __forceinline__ int SW(int j, int c) {
    return (j << 7) + (c ^ ((j & 7) << 2));
}

__global__ __launch_bounds__(512, 4) void tcn_fused(
    const float* __restrict__ x,
    const float* __restrict__ sc_w,
    const float* __restrict__ pw_w0,
    const float* __restrict__ pw_w_rest,
    const float* __restrict__ pw_b,
    const float* __restrict__ bn_g,
    const float* __restrict__ bn_b,
    const float* __restrict__ bn_m,
    const float* __restrict__ bn_v,
    const float* __restrict__ res_w,
    const float* __restrict__ res_b,
    const float* __restrict__ out_w,
    const float* __restrict__ out_b,
    float* __restrict__ out)
{
    __shared__ __align__(16) float lds[128 * 128];   // 64 KB -> 2 blocks/CU

    const int tile = blockIdx.x;
    const int b    = blockIdx.y;
    const int s    = tile * TL;
    const int tid  = threadIdx.x;
    const int lane = tid & 63;
    const int wave = tid >> 6;

    // ---- stage x[b, 0:64, s-30 : s+98) transposed: lds[j][c] = x[c][s-30+j] ----
    const float* xb = x + (size_t)b * CIN * L;
    #pragma unroll
    for (int it = 0; it < 16; ++it) {
        const int idx = it * 512 + tid;
        const int c = idx >> 7;          // channel
        const int j = idx & 127;         // position column
        const int p = s - 30 + j;
        float v = 0.0f;                  // causal left pad = 0
        if (p >= 0)
            v = xb[(size_t)c * L + (p < L ? p : L - 1)];  // right-clamp masked at output
        lds[SW(j, c)] = v;
    }
    __syncthreads();

    const int obase = __builtin_amdgcn_readfirstlane(wave << 4);

    auto ld4 = [&](int j, int cb) -> float4 {
        return *(const float4*)&lds[SW(j, cb)];
    };

    // =================== layer 0 (CIN=64, dil=1, j0=2) + residual 1x1 ===================
    {
        const float w0 = sc_w[0], w1 = sc_w[1], w2 = sc_w[2];
        const int jA = 2 + lane;                  // < 126 always
        const int jB = 66 + lane;
        const bool aB = (jB < NCOL);
        const int jcB = aB ? jB : (NCOL - 1);

        float acc[16][2], accR[16][2];
        #pragma unroll
        for (int q = 0; q < 16; ++q) {
            acc[q][0] = 0.f; acc[q][1] = 0.f;
            accR[q][0] = 0.f; accR[q][1] = 0.f;
        }

        for (int c4 = 0; c4 < CIN / 4; ++c4) {
            const int cb = c4 * 4;
            const float4 A0 = ld4(jA, cb),  A1 = ld4(jA - 1, cb),  A2 = ld4(jA - 2, cb);
            const float4 B0 = ld4(jcB, cb), B1 = ld4(jcB - 1, cb), B2 = ld4(jcB - 2, cb);
            const float a0[4] = {A0.x, A0.y, A0.z, A0.w};
            const float a1[4] = {A1.x, A1.y, A1.z, A1.w};
            const float a2[4] = {A2.x, A2.y, A2.z, A2.w};
            const float b0[4] = {B0.x, B0.y, B0.z, B0.w};
            const float b1[4] = {B1.x, B1.y, B1.z, B1.w};
            const float b2[4] = {B2.x, B2.y, B2.z, B2.w};
            float d[4][2], t0[4][2];
            #pragma unroll
            for (int k = 0; k < 4; ++k) {
                d[k][0] = fmaf(w2, a0[k], fmaf(w1, a1[k], w0 * a2[k]));
                d[k][1] = fmaf(w2, b0[k], fmaf(w1, b1[k], w0 * b2[k]));
                t0[k][0] = a0[k];
                t0[k][1] = b0[k];
            }
            #pragma unroll
            for (int g = 0; g < 2; ++g) {                   // 8-row W groups: <=32 live SGPRs
                const int ob = g * 8;
                float4 wv[8];
                #pragma unroll
                for (int q = 0; q < 8; ++q)
                    wv[q] = *(const float4*)(pw_w0 + (size_t)(obase + ob + q) * CIN + cb);
                #pragma unroll
                for (int q = 0; q < 8; ++q) {
                    #pragma unroll
                    for (int ph = 0; ph < 2; ++ph) {
                        float a = acc[ob + q][ph];
                        a = fmaf(wv[q].x, d[0][ph], a);
                        a = fmaf(wv[q].y, d[1][ph], a);
                        a = fmaf(wv[q].z, d[2][ph], a);
                        a = fmaf(wv[q].w, d[3][ph], a);
                        acc[ob + q][ph] = a;
                    }
                }
            }
            #pragma unroll
            for (int g = 0; g < 2; ++g) {
                const int ob = g * 8;
                float4 rv[8];
                #pragma unroll
                for (int q = 0; q < 8; ++q)
                    rv[q] = *(const float4*)(res_w + (size_t)(obase + ob + q) * CIN + cb);
                #pragma unroll
                for (int q = 0; q < 8; ++q) {
                    #pragma unroll
                    for (int ph = 0; ph < 2; ++ph) {
                        float a = accR[ob + q][ph];
                        a = fmaf(rv[q].x, t0[0][ph], a);
                        a = fmaf(rv[q].y, t0[1][ph], a);
                        a = fmaf(rv[q].z, t0[2][ph], a);
                        a = fmaf(rv[q].w, t0[3][ph], a);
                        accR[ob + q][ph] = a;
                    }
                }
            }
        }
        #pragma unroll
        for (int q = 0; q < 16; ++q) {
            const int o = obase + q;
            const float A  = bn_g[o] * rsqrtf(bn_v[o] + EPS);
            const float Cc = fmaf(A, pw_b[o] - bn_m[o], bn_b[o]);
            const float y0 = fmaxf(fmaf(A, acc[q][0], Cc), 0.0f);
            const float y1 = fmaxf(fmaf(A, acc[q][1], Cc), 0.0f);
            float v0 = fmaxf(y0 + accR[q][0] + res_b[o], 0.0f);
            float v1 = fmaxf(y1 + accR[q][1] + res_b[o], 0.0f);
            if (s - 30 + jA < 0) v0 = 0.0f;        // true causal zero-pad (tile 0)
            acc[q][0] = v0;
            acc[q][1] = v1;                        // jB>=66 -> never padded
        }
        __syncthreads();                           // all reads of x done
        #pragma unroll
        for (int k = 0; k < 4; ++k)
            *(float4*)&lds[SW(jA, obase + 4 * k)] =
                make_float4(acc[4*k][0], acc[4*k+1][0], acc[4*k+2][0], acc[4*k+3][0]);
        if (aB) {
            #pragma unroll
            for (int k = 0; k < 4; ++k)
                *(float4*)&lds[SW(jB, obase + 4 * k)] =
                    make_float4(acc[4*k][1], acc[4*k+1][1], acc[4*k+2][1], acc[4*k+3][1]);
        }
        __syncthreads();                           // h1 visible
    }

    // =================== layers 1..3 (C=128, dil=2^li, j0=4<<li - 2) ===================
    #pragma unroll
    for (int li = 1; li < 4; ++li) {
        const int dil = 1 << li;
        const int j0  = (4 << li) - 2;             // 6, 14, 30
        const float w0 = sc_w[li * 3 + 0], w1 = sc_w[li * 3 + 1], w2 = sc_w[li * 3 + 2];
        const float* __restrict__ W = pw_w_rest + (size_t)(li - 1) * H * H;
        const int jA = j0 + lane;                  // <= 93 < 126 always
        const int jB = j0 + 64 + lane;
        const bool aB = (jB < NCOL);
        const int jcB = aB ? jB : (NCOL - 1);

        float acc[16][2];
        #pragma unroll
        for (int q = 0; q < 16; ++q) { acc[q][0] = 0.f; acc[q][1] = 0.f; }

        for (int c4 = 0; c4 < H / 4; ++c4) {
            const int cb = c4 * 4;
            const float4 A0 = ld4(jA, cb),  A1 = ld4(jA - dil, cb),  A2 = ld4(jA - 2 * dil, cb);
            const float4 B0 = ld4(jcB, cb), B1 = ld4(jcB - dil, cb), B2 = ld4(jcB - 2 * dil, cb);
            const float a0[4] = {A0.x, A0.y, A0.z, A0.w};
            const float a1[4] = {A1.x, A1.y, A1.z, A1.w};
            const float a2[4] = {A2.x, A2.y, A2.z, A2.w};
            const float b0[4] = {B0.x, B0.y, B0.z, B0.w};
            const float b1[4] = {B1.x, B1.y, B1.z, B1.w};
            const float b2[4] = {B2.x, B2.y, B2.z, B2.w};
            float d[4][2];
            #pragma unroll
            for (int k = 0; k < 4; ++k) {
                d[k][0] = fmaf(w2, a0[k], fmaf(w1, a1[k], w0 * a2[k]));
                d[k][1] = fmaf(w2, b0[k], fmaf(w1, b1[k], w0 * b2[k]));
            }
            #pragma unroll
            for (int g = 0; g < 2; ++g) {
                const int ob = g * 8;
                float4 wv[8];
                #pragma unroll
                for (int q = 0; q < 8; ++q)
                    wv[q] = *(const float4*)(W + (size_t)(obase + ob + q) * H + cb);
                #pragma unroll
                for (int q = 0; q < 8; ++q) {
                    #pragma unroll
                    for (int ph = 0; ph < 2; ++ph) {
                        float a = acc[ob + q][ph];
                        a = fmaf(wv[q].x, d[0][ph], a);
                        a = fmaf(wv[q].y, d[1][ph], a);
                        a = fmaf(wv[q].z, d[2][ph], a);
                        a = fmaf(wv[q].w, d[3][ph], a);
                        acc[ob + q][ph] = a;
                    }
                }
            }
        }
        // identity residual — read pre-overwrite (b128)
        float rA[16], rB[16];
        #pragma unroll
        for (int k = 0; k < 4; ++k) {
            const float4 vA = ld4(jA, obase + 4 * k);
            const float4 vB = ld4(jcB, obase + 4 * k);
            rA[4*k] = vA.x; rA[4*k+1] = vA.y; rA[4*k+2] = vA.z; rA[4*k+3] = vA.w;
            rB[4*k] = vB.x; rB[4*k+1] = vB.y; rB[4*k+2] = vB.z; rB[4*k+3] = vB.w;
        }
        #pragma unroll
        for (int q = 0; q < 16; ++q) {
            const int o = obase + q;
            const float A  = bn_g[li * H + o] * rsqrtf(bn_v[li * H + o] + EPS);
            const float Cc = fmaf(A, pw_b[li * H + o] - bn_m[li * H + o], bn_b[li * H + o]);
            const float y0 = fmaxf(fmaf(A, acc[q][0], Cc), 0.0f);
            const float y1 = fmaxf(fmaf(A, acc[q][1], Cc), 0.0f);
            float v0 = fmaxf(y0 + rA[q], 0.0f);
            float v1 = fmaxf(y1 + rB[q], 0.0f);
            if (s - 30 + jA < 0) v0 = 0.0f;        // zero-pad halo (tile 0 only)
            acc[q][0] = v0;
            acc[q][1] = v1;
        }
        __syncthreads();                           // all reads of h_li done
        #pragma unroll
        for (int k = 0; k < 4; ++k)
            *(float4*)&lds[SW(jA, obase + 4 * k)] =
                make_float4(acc[4*k][0], acc[4*k+1][0], acc[4*k+2][0], acc[4*k+3][0]);
        if (aB) {
            #pragma unroll
            for (int k = 0; k < 4; ++k)
                *(float4*)&lds[SW(jB, obase + 4 * k)] =
                    make_float4(acc[4*k][1], acc[4*k+1][1], acc[4*k+2][1], acc[4*k+3][1]);
        }
        __syncthreads();                           // h_{li+1} visible
    }

    // =================== output projection ===================
    if (tid < TL) {
        const int p = s + tid;
        if (p < L) {
            const int r = 30 + tid;
            float a0 = 0.0f, a1 = 0.0f, a2 = 0.0f, a3 = 0.0f;
            #pragma unroll
            for (int o = 0; o < H; o += 4) {
                const float4 wv = *(const float4*)(out_w + o);
                const float4 hv = ld4(r, o);
                a0 = fmaf(wv.x, hv.x, a0);
                a1 = fmaf(wv.y, hv.y, a1);
                a2 = fmaf(wv.z, hv.z, a2);
                a3 = fmaf(wv.w, hv.w, a3);
            }
            out[(size_t)b * L + p] = ((a0 + a1) + (a2 + a3)) + out_b[0];
        }
    }
}

extern "C" void kernel_launch(void* const* d_in, const int* in_sizes, int n_in,
                              void* d_out, int out_size, void* d_ws, size_t ws_size,
                              hipStream_t stream) {
    const float* x         = (const float*)d_in[0];
    const float* sc_w      = (const float*)d_in[1];
    const float* pw_w0     = (const float*)d_in[2];
    const float* pw_w_rest = (const float*)d_in[3];
    const float* pw_b      = (const float*)d_in[4];
    const float* bn_g      = (const float*)d_in[5];
    const float* bn_b      = (const float*)d_in[6];
    const float* bn_m      = (const float*)d_in[7];
    const float* bn_v      = (const float*)d_in[8];
    const float* res_w     = (const float*)d_in[9];
    const float* res_b     = (const float*)d_in[10];
    const float* out_w     = (const float*)d_in[11];
    const float* out_b     = (const float*)d_in[12];
    float* out = (float*)d_out;

    dim3 grid(NTILES, B);
    tcn_fused<<<grid, 512, 0, stream>>>(x, sc_w, pw_w0, pw_w_rest, pw_b,
                                        bn_g, bn_b, bn_m, bn_v,
                                        res_w, res_b, out_w, out_b, out);
}